// Round 1
// baseline (10618.677 us; speedup 1.0000x reference)
//
#include <hip/hip_runtime.h>
#include <math.h>

#define B_TOT 2048
#define T_LEN 512
#define HDIM 64
#define NGATE 256
#define NB 8        // batch elements per block
#define NTH 512     // threads per block (8 waves)
#define FC1 50

__device__ __forceinline__ float sigm(float x) { return 1.0f / (1.0f + __expf(-x)); }
__device__ __forceinline__ float tanh_(float x) { return 2.0f / (1.0f + __expf(-2.0f * x)) - 1.0f; }

// One LSTM layer, persistent over all T steps. One block handles NB batch rows.
// Thread mapping phase B (gate matmul): r = tid&255 (gate row), half = tid>>8 (k-half).
//   Each thread holds W_hh[r][32*half .. +32) and W_ih[r][...] in registers (64 VGPRs).
// Thread mapping phase C (cell update): b2 = tid>>6, j = tid&63 -> owns c[b2][j] in a register.
template<bool FIRST>
__global__ __launch_bounds__(NTH, 1)
void lstm_layer(const float* __restrict__ x_in,   // FIRST: [B,T,3] else [B,T,64] (may alias seq_out)
                const float* __restrict__ w_ih,   // FIRST: [256,3] else [256,64]
                const float* __restrict__ w_hh,   // [256,64]
                const float* __restrict__ b_ih,   // [256]
                const float* __restrict__ b_hh,   // [256]
                float* __restrict__ seq_out)      // [B,T,64]
{
    const int tid  = threadIdx.x;
    const int r    = tid & 255;
    const int half = tid >> 8;
    const int bbase = blockIdx.x * NB;
    const int b2 = tid >> 6;
    const int j  = tid & 63;

    __shared__ __align__(16) float h_lds[NB][HDIM];       // 2 KB
    __shared__ __align__(16) float x_lds[NB][HDIM];       // 2 KB
    __shared__ __align__(16) float part[NB][2 * NGATE];   // 16 KB
    __shared__ float bias_lds[NGATE];                     // 1 KB

    // ---- load weights into registers ----
    float whh[32], wih[32];
#pragma unroll
    for (int q = 0; q < 8; ++q) {
        float4 v = *(const float4*)(w_hh + (size_t)r * HDIM + half * 32 + q * 4);
        whh[q*4+0] = v.x; whh[q*4+1] = v.y; whh[q*4+2] = v.z; whh[q*4+3] = v.w;
    }
    if (FIRST) {
#pragma unroll
        for (int q = 0; q < 32; ++q) wih[q] = 0.0f;
        if (half == 0) {
            wih[0] = w_ih[r*3+0]; wih[1] = w_ih[r*3+1]; wih[2] = w_ih[r*3+2];
        }
    } else {
#pragma unroll
        for (int q = 0; q < 8; ++q) {
            float4 v = *(const float4*)(w_ih + (size_t)r * HDIM + half * 32 + q * 4);
            wih[q*4+0] = v.x; wih[q*4+1] = v.y; wih[q*4+2] = v.z; wih[q*4+3] = v.w;
        }
    }
    if (half == 0) bias_lds[r] = b_ih[r] + b_hh[r];
    h_lds[b2][j] = 0.0f;
    float c = 0.0f;

    // prefetch x(t=0)
    float xreg = 0.0f;
    if (FIRST) {
        if (tid < NB * 3) xreg = x_in[(size_t)(bbase + tid / 3) * T_LEN * 3 + (tid % 3)];
    } else {
        xreg = x_in[(size_t)(bbase + b2) * T_LEN * HDIM + j];
    }
    __syncthreads();

    for (int t = 0; t < T_LEN; ++t) {
        // ---- phase A: commit x(t) to LDS (from prefetch reg) ----
        if (FIRST) {
            if (tid < NB * 3) x_lds[tid / 3][tid % 3] = xreg;
        } else {
            x_lds[b2][j] = xreg;
        }
        // ---- phase C(t-1): cell update from previous step's partials ----
        if (t > 0) {
            float gi = part[b2][j]       + part[b2][NGATE + j]       + bias_lds[j];
            float gf = part[b2][64 + j]  + part[b2][NGATE + 64 + j]  + bias_lds[64 + j];
            float gg = part[b2][128 + j] + part[b2][NGATE + 128 + j] + bias_lds[128 + j];
            float go = part[b2][192 + j] + part[b2][NGATE + 192 + j] + bias_lds[192 + j];
            float iv = sigm(gi), fv = sigm(gf), gv = tanh_(gg), ov = sigm(go);
            c = fv * c + iv * gv;
            float hv = ov * tanh_(c);
            h_lds[b2][j] = hv;
            seq_out[(size_t)(bbase + b2) * T_LEN * HDIM + (size_t)(t - 1) * HDIM + j] = hv;
        }
        __syncthreads();

        // prefetch x(t+1) — hidden under phase B
        if (t + 1 < T_LEN) {
            if (FIRST) {
                if (tid < NB * 3)
                    xreg = x_in[(size_t)(bbase + tid / 3) * T_LEN * 3 + (size_t)(t + 1) * 3 + (tid % 3)];
            } else {
                xreg = x_in[(size_t)(bbase + b2) * T_LEN * HDIM + (size_t)(t + 1) * HDIM + j];
            }
        }

        // ---- phase B: partial gate pre-activations ----
        float acc[NB];
#pragma unroll
        for (int b = 0; b < NB; ++b) acc[b] = 0.0f;
        if (FIRST) {
            if (half == 0) {
#pragma unroll
                for (int b = 0; b < NB; ++b)
                    acc[b] = wih[0] * x_lds[b][0] + wih[1] * x_lds[b][1] + wih[2] * x_lds[b][2];
            }
#pragma unroll
            for (int q = 0; q < 8; ++q) {
#pragma unroll
                for (int b = 0; b < NB; ++b) {
                    float4 hv = *(const float4*)(&h_lds[b][half * 32 + q * 4]);
                    acc[b] += whh[q*4+0]*hv.x + whh[q*4+1]*hv.y + whh[q*4+2]*hv.z + whh[q*4+3]*hv.w;
                }
            }
        } else {
#pragma unroll
            for (int q = 0; q < 8; ++q) {
#pragma unroll
                for (int b = 0; b < NB; ++b) {
                    float4 hv = *(const float4*)(&h_lds[b][half * 32 + q * 4]);
                    float4 xv = *(const float4*)(&x_lds[b][half * 32 + q * 4]);
                    acc[b] += whh[q*4+0]*hv.x + whh[q*4+1]*hv.y + whh[q*4+2]*hv.z + whh[q*4+3]*hv.w
                            + wih[q*4+0]*xv.x + wih[q*4+1]*xv.y + wih[q*4+2]*xv.z + wih[q*4+3]*xv.w;
                }
            }
        }
#pragma unroll
        for (int b = 0; b < NB; ++b) part[b][half * NGATE + r] = acc[b];
        __syncthreads();
    }

    // ---- final phase C for t = T-1 ----
    {
        float gi = part[b2][j]       + part[b2][NGATE + j]       + bias_lds[j];
        float gf = part[b2][64 + j]  + part[b2][NGATE + 64 + j]  + bias_lds[64 + j];
        float gg = part[b2][128 + j] + part[b2][NGATE + 128 + j] + bias_lds[128 + j];
        float go = part[b2][192 + j] + part[b2][NGATE + 192 + j] + bias_lds[192 + j];
        float iv = sigm(gi), fv = sigm(gf), gv = tanh_(gg), ov = sigm(go);
        c = fv * c + iv * gv;
        float hv = ov * tanh_(c);
        seq_out[(size_t)(bbase + b2) * T_LEN * HDIM + (size_t)(T_LEN - 1) * HDIM + j] = hv;
    }
}

// FC head: out[b] = fc2_b + fc2_w . relu(fc1_b + fc1_w . h_T[b])
__global__ __launch_bounds__(256, 1)
void fc_head(const float* __restrict__ seq,
             const float* __restrict__ fc1_w, const float* __restrict__ fc1_b,
             const float* __restrict__ fc2_w, const float* __restrict__ fc2_b,
             float* __restrict__ out)
{
    __shared__ float w1[FC1 * HDIM];
    __shared__ float b1[FC1];
    __shared__ float w2[FC1];
    const int tid = threadIdx.x;
    for (int i = tid; i < FC1 * HDIM; i += 256) w1[i] = fc1_w[i];
    if (tid < FC1) { b1[tid] = fc1_b[tid]; w2[tid] = fc2_w[tid]; }
    __syncthreads();

    const int b = blockIdx.x * 256 + tid;
    float h[HDIM];
    const float4* hp = (const float4*)(seq + (size_t)b * T_LEN * HDIM + (size_t)(T_LEN - 1) * HDIM);
#pragma unroll
    for (int q = 0; q < 16; ++q) {
        float4 v = hp[q];
        h[q*4+0] = v.x; h[q*4+1] = v.y; h[q*4+2] = v.z; h[q*4+3] = v.w;
    }
    float acc2 = fc2_b[0];
    for (int m = 0; m < FC1; ++m) {
        float a = b1[m];
#pragma unroll
        for (int q = 0; q < HDIM; ++q) a += w1[m * HDIM + q] * h[q];
        acc2 += w2[m] * fmaxf(a, 0.0f);
    }
    out[b] = acc2;
}

extern "C" void kernel_launch(void* const* d_in, const int* in_sizes, int n_in,
                              void* d_out, int out_size, void* d_ws, size_t ws_size,
                              hipStream_t stream) {
    const float* x         = (const float*)d_in[0];
    const float* w_ih0     = (const float*)d_in[1];
    const float* w_ih_rest = (const float*)d_in[2];
    const float* w_hh      = (const float*)d_in[3];
    const float* b_ih      = (const float*)d_in[4];
    const float* b_hh      = (const float*)d_in[5];
    const float* fc1_w     = (const float*)d_in[6];
    const float* fc1_b     = (const float*)d_in[7];
    const float* fc2_w     = (const float*)d_in[8];
    const float* fc2_b     = (const float*)d_in[9];
    float* seq = (float*)d_ws;   // [B, T, 64] f32 = 256 MB
    float* out = (float*)d_out;

    dim3 grid(B_TOT / NB), block(NTH);
    lstm_layer<true><<<grid, block, 0, stream>>>(x, w_ih0, w_hh, b_ih, b_hh, seq);
    for (int l = 1; l < 5; ++l) {
        lstm_layer<false><<<grid, block, 0, stream>>>(
            seq,
            w_ih_rest + (size_t)(l - 1) * NGATE * HDIM,
            w_hh + (size_t)l * NGATE * HDIM,
            b_ih + (size_t)l * NGATE,
            b_hh + (size_t)l * NGATE,
            seq);
    }
    fc_head<<<dim3(B_TOT / 256), dim3(256), 0, stream>>>(seq, fc1_w, fc1_b, fc2_w, fc2_b, out);
}

// Round 2
// 5817.348 us; speedup vs baseline: 1.8253x; 1.8253x over previous
//
#include <hip/hip_runtime.h>
#include <math.h>

#define B_TOT 2048
#define T_LEN 512
#define HDIM 64
#define NGATE 256
#define NB 4        // batch elements per block
#define NTH 512     // threads per block (8 waves)
#define FC1 50

__device__ __forceinline__ float sigm(float x) { return 1.0f / (1.0f + __expf(-x)); }
__device__ __forceinline__ float tanh_(float x) { return 2.0f / (1.0f + __expf(-2.0f * x)) - 1.0f; }

// One LSTM layer, persistent over all T steps. One block handles NB batch rows.
// Phase B mapping: r = tid&255 (gate row), half = tid>>8 (k-half). Each thread
// holds W_hh[r][32*half..+32) (+ W_ih same) in registers, PINNED via opaque asm
// so the compiler cannot sink the loads back into the t-loop (R1: VGPR=52 proved
// it rematerialized weight loads every step).
// Phase C mapping (tid<256): b2 = tid>>6, j = tid&63 owns c[b2][j] in a register.
template<bool FIRST>
__global__ __launch_bounds__(NTH, 4)   // 4 waves/EU -> 2 blocks/CU, VGPR cap 128
void lstm_layer(const float* __restrict__ x_in,   // FIRST: [B,T,3] else [B,T,64]
                const float* __restrict__ w_ih,   // FIRST: [256,3] else [256,64]
                const float* __restrict__ w_hh,   // [256,64]
                const float* __restrict__ b_ih,   // [256]
                const float* __restrict__ b_hh,   // [256]
                float* __restrict__ seq_out)      // [B,T,64]
{
    const int tid  = threadIdx.x;
    const int r    = tid & 255;
    const int half = tid >> 8;
    const int bbase = blockIdx.x * NB;
    const int b2 = (tid >> 6) & 3;
    const int j  = tid & 63;

    __shared__ __align__(16) float h_lds[NB][HDIM];       // 1 KB
    __shared__ __align__(16) float x_lds[NB][HDIM];       // 1 KB
    __shared__ __align__(16) float part[NB][2 * NGATE];   // 8 KB
    __shared__ float bias_lds[NGATE];                     // 1 KB

    // ---- load weights into registers and PIN them ----
    float whh[32];
#pragma unroll
    for (int q = 0; q < 8; ++q) {
        float4 v = *(const float4*)(w_hh + (size_t)r * HDIM + half * 32 + q * 4);
        whh[q*4+0] = v.x; whh[q*4+1] = v.y; whh[q*4+2] = v.z; whh[q*4+3] = v.w;
    }
    float wih[FIRST ? 4 : 32];
    if (FIRST) {
#pragma unroll
        for (int q = 0; q < 4; ++q) wih[q] = 0.0f;
        if (half == 0) {
            wih[0] = w_ih[r*3+0]; wih[1] = w_ih[r*3+1]; wih[2] = w_ih[r*3+2];
        }
    } else {
#pragma unroll
        for (int q = 0; q < 8; ++q) {
            float4 v = *(const float4*)(w_ih + (size_t)r * HDIM + half * 32 + q * 4);
            wih[q*4+0] = v.x; wih[q*4+1] = v.y; wih[q*4+2] = v.z; wih[q*4+3] = v.w;
        }
    }
    // Opaque pin: value becomes unknown to the compiler -> cannot re-load from
    // global inside the loop; must stay in a VGPR.
#pragma unroll
    for (int q = 0; q < 32; ++q) asm volatile("" : "+v"(whh[q]));
#pragma unroll
    for (int q = 0; q < (FIRST ? 4 : 32); ++q) asm volatile("" : "+v"(wih[q]));

    if (half == 0) bias_lds[r] = b_ih[r] + b_hh[r];
    if (tid < NB * HDIM) h_lds[b2][j] = 0.0f;
    float c = 0.0f;

    // prefetch x(t=0)
    float4 xreg = make_float4(0.f, 0.f, 0.f, 0.f);
    if (FIRST) {
        if (tid < NB * 3) xreg.x = x_in[(size_t)(bbase + tid / 3) * T_LEN * 3 + (tid % 3)];
    } else {
        // 64 threads: b = tid>>4, qq = tid&15 -> float4 of x[b][t][qq*4..]
        if (tid < 64)
            xreg = *(const float4*)(x_in + (size_t)(bbase + (tid >> 4)) * T_LEN * HDIM + (tid & 15) * 4);
    }
    __syncthreads();

    for (int t = 0; t < T_LEN; ++t) {
        // ---- phase A: commit x(t) to LDS ----
        if (FIRST) {
            if (tid < NB * 3) x_lds[tid / 3][tid % 3] = xreg.x;
        } else {
            if (tid < 64) *(float4*)(&x_lds[tid >> 4][(tid & 15) * 4]) = xreg;
        }
        // ---- phase C(t-1): cell update from previous step's partials ----
        if (t > 0 && tid < NB * HDIM) {
            float gi = part[b2][j]       + part[b2][NGATE + j]       + bias_lds[j];
            float gf = part[b2][64 + j]  + part[b2][NGATE + 64 + j]  + bias_lds[64 + j];
            float gg = part[b2][128 + j] + part[b2][NGATE + 128 + j] + bias_lds[128 + j];
            float go = part[b2][192 + j] + part[b2][NGATE + 192 + j] + bias_lds[192 + j];
            float iv = sigm(gi), fv = sigm(gf), gv = tanh_(gg), ov = sigm(go);
            c = fv * c + iv * gv;
            float hv = ov * tanh_(c);
            h_lds[b2][j] = hv;
            seq_out[(size_t)(bbase + b2) * T_LEN * HDIM + (size_t)(t - 1) * HDIM + j] = hv;
        }
        __syncthreads();

        // prefetch x(t+1) — hidden under phase B
        if (t + 1 < T_LEN) {
            if (FIRST) {
                if (tid < NB * 3)
                    xreg.x = x_in[(size_t)(bbase + tid / 3) * T_LEN * 3 + (size_t)(t + 1) * 3 + (tid % 3)];
            } else {
                if (tid < 64)
                    xreg = *(const float4*)(x_in + (size_t)(bbase + (tid >> 4)) * T_LEN * HDIM
                                            + (size_t)(t + 1) * HDIM + (tid & 15) * 4);
            }
        }

        // ---- phase B: partial gate pre-activations ----
        float acc[NB];
#pragma unroll
        for (int b = 0; b < NB; ++b) acc[b] = 0.0f;
        if (FIRST) {
            if (half == 0) {
#pragma unroll
                for (int b = 0; b < NB; ++b)
                    acc[b] = wih[0] * x_lds[b][0] + wih[1] * x_lds[b][1] + wih[2] * x_lds[b][2];
            }
#pragma unroll
            for (int q = 0; q < 8; ++q) {
#pragma unroll
                for (int b = 0; b < NB; ++b) {
                    float4 hv = *(const float4*)(&h_lds[b][half * 32 + q * 4]);
                    acc[b] += whh[q*4+0]*hv.x + whh[q*4+1]*hv.y + whh[q*4+2]*hv.z + whh[q*4+3]*hv.w;
                }
            }
        } else {
#pragma unroll
            for (int q = 0; q < 8; ++q) {
#pragma unroll
                for (int b = 0; b < NB; ++b) {
                    float4 hv = *(const float4*)(&h_lds[b][half * 32 + q * 4]);
                    float4 xv = *(const float4*)(&x_lds[b][half * 32 + q * 4]);
                    acc[b] += whh[q*4+0]*hv.x + whh[q*4+1]*hv.y + whh[q*4+2]*hv.z + whh[q*4+3]*hv.w
                            + wih[q*4+0]*xv.x + wih[q*4+1]*xv.y + wih[q*4+2]*xv.z + wih[q*4+3]*xv.w;
                }
            }
        }
#pragma unroll
        for (int b = 0; b < NB; ++b) part[b][half * NGATE + r] = acc[b];
        __syncthreads();
    }

    // ---- final phase C for t = T-1 ----
    if (tid < NB * HDIM) {
        float gi = part[b2][j]       + part[b2][NGATE + j]       + bias_lds[j];
        float gf = part[b2][64 + j]  + part[b2][NGATE + 64 + j]  + bias_lds[64 + j];
        float gg = part[b2][128 + j] + part[b2][NGATE + 128 + j] + bias_lds[128 + j];
        float go = part[b2][192 + j] + part[b2][NGATE + 192 + j] + bias_lds[192 + j];
        float iv = sigm(gi), fv = sigm(gf), gv = tanh_(gg), ov = sigm(go);
        c = fv * c + iv * gv;
        float hv = ov * tanh_(c);
        seq_out[(size_t)(bbase + b2) * T_LEN * HDIM + (size_t)(T_LEN - 1) * HDIM + j] = hv;
    }
}

// FC head: out[b] = fc2_b + fc2_w . relu(fc1_b + fc1_w . h_T[b])
__global__ __launch_bounds__(256, 1)
void fc_head(const float* __restrict__ seq,
             const float* __restrict__ fc1_w, const float* __restrict__ fc1_b,
             const float* __restrict__ fc2_w, const float* __restrict__ fc2_b,
             float* __restrict__ out)
{
    __shared__ float w1[FC1 * HDIM];
    __shared__ float b1[FC1];
    __shared__ float w2[FC1];
    const int tid = threadIdx.x;
    for (int i = tid; i < FC1 * HDIM; i += 256) w1[i] = fc1_w[i];
    if (tid < FC1) { b1[tid] = fc1_b[tid]; w2[tid] = fc2_w[tid]; }
    __syncthreads();

    const int b = blockIdx.x * 256 + tid;
    float h[HDIM];
    const float4* hp = (const float4*)(seq + (size_t)b * T_LEN * HDIM + (size_t)(T_LEN - 1) * HDIM);
#pragma unroll
    for (int q = 0; q < 16; ++q) {
        float4 v = hp[q];
        h[q*4+0] = v.x; h[q*4+1] = v.y; h[q*4+2] = v.z; h[q*4+3] = v.w;
    }
    float acc2 = fc2_b[0];
    for (int m = 0; m < FC1; ++m) {
        float a = b1[m];
#pragma unroll
        for (int q = 0; q < HDIM; ++q) a += w1[m * HDIM + q] * h[q];
        acc2 += w2[m] * fmaxf(a, 0.0f);
    }
    out[b] = acc2;
}

extern "C" void kernel_launch(void* const* d_in, const int* in_sizes, int n_in,
                              void* d_out, int out_size, void* d_ws, size_t ws_size,
                              hipStream_t stream) {
    const float* x         = (const float*)d_in[0];
    const float* w_ih0     = (const float*)d_in[1];
    const float* w_ih_rest = (const float*)d_in[2];
    const float* w_hh      = (const float*)d_in[3];
    const float* b_ih      = (const float*)d_in[4];
    const float* b_hh      = (const float*)d_in[5];
    const float* fc1_w     = (const float*)d_in[6];
    const float* fc1_b     = (const float*)d_in[7];
    const float* fc2_w     = (const float*)d_in[8];
    const float* fc2_b     = (const float*)d_in[9];
    float* seq = (float*)d_ws;   // [B, T, 64] f32 = 256 MB
    float* out = (float*)d_out;

    dim3 grid(B_TOT / NB), block(NTH);
    lstm_layer<true><<<grid, block, 0, stream>>>(x, w_ih0, w_hh, b_ih, b_hh, seq);
    for (int l = 1; l < 5; ++l) {
        lstm_layer<false><<<grid, block, 0, stream>>>(
            seq,
            w_ih_rest + (size_t)(l - 1) * NGATE * HDIM,
            w_hh + (size_t)l * NGATE * HDIM,
            b_ih + (size_t)l * NGATE,
            b_hh + (size_t)l * NGATE,
            seq);
    }
    fc_head<<<dim3(B_TOT / 256), dim3(256), 0, stream>>>(seq, fc1_w, fc1_b, fc2_w, fc2_b, out);
}

// Round 3
// 3054.384 us; speedup vs baseline: 3.4765x; 1.9046x over previous
//
#include <hip/hip_runtime.h>
#include <math.h>

#define B_TOT 2048
#define T_LEN 512
#define HDIM 64
#define FC1 50

typedef __bf16 bf16x8 __attribute__((ext_vector_type(8)));
typedef float f32x4 __attribute__((ext_vector_type(4)));
typedef unsigned int u32x4 __attribute__((ext_vector_type(4)));
typedef unsigned short u16x8 __attribute__((ext_vector_type(8)));

__device__ __forceinline__ float sigm(float x) { return 1.0f / (1.0f + __expf(-x)); }
__device__ __forceinline__ float tanh_(float x) { return 2.0f / (1.0f + __expf(-2.0f * x)) - 1.0f; }

// LSTM layer via bf16 MFMA, split-precision state (h = hi + lo bf16 pair).
// Block = 16 batch rows, 4 waves; wave w owns units [16w, 16w+16).
// Per step, per wave, per gate-type g (i,f,g,o): acc[16x16] = sum over K of
//   mfma(h_hi) + mfma(h_lo) + mfma(x_hi) + mfma(x_lo).
// A-frag: lane row m = lane&15, k-slot (c=lane>>4, e): k = kk*32 + 8c + e.
// B-frag: lane col n = lane&15, same k mapping (identical phi => any hardware
//   k-slot permutation cancels between A and B).
// C/D (m89-verified): col = lane&15, row = 4*(lane>>4) + reg.
// Cell state c stays fp32 in registers; gates fp32; h split to bf16 pair for
// LDS exchange (packed hi|lo<<16, XOR-swizzled) and for the global seq pair.
#define STEP(T0, P)                                                            \
  {                                                                            \
    const int swz = (nn & 7) << 2;                                             \
    bf16x8 ahh[2], ahl[2];                                                     \
    _Pragma("unroll")                                                          \
    for (int kk = 0; kk < 2; ++kk) {                                           \
      int ub = kk * 32 + 8 * cg;                                               \
      u32x4 p0 = *(const u32x4*)&hbuf[P][nn * 64 + ((ub + 0) ^ swz)];          \
      u32x4 p1 = *(const u32x4*)&hbuf[P][nn * 64 + ((ub + 4) ^ swz)];          \
      u16x8 uh, ul;                                                            \
      _Pragma("unroll")                                                        \
      for (int e = 0; e < 4; ++e) {                                            \
        uh[e]     = (unsigned short)(p0[e] & 0xffffu);                         \
        ul[e]     = (unsigned short)(p0[e] >> 16);                             \
        uh[4 + e] = (unsigned short)(p1[e] & 0xffffu);                         \
        ul[4 + e] = (unsigned short)(p1[e] >> 16);                             \
      }                                                                        \
      ahh[kk] = __builtin_bit_cast(bf16x8, uh);                                \
      ahl[kk] = __builtin_bit_cast(bf16x8, ul);                                \
    }                                                                          \
    f32x4 accs[4];                                                             \
    _Pragma("unroll")                                                          \
    for (int g = 0; g < 4; ++g) {                                              \
      f32x4 a = {0.f, 0.f, 0.f, 0.f};                                         \
      a = __builtin_amdgcn_mfma_f32_16x16x32_bf16(ahh[0], bhh[g][0], a, 0, 0, 0); \
      a = __builtin_amdgcn_mfma_f32_16x16x32_bf16(ahh[1], bhh[g][1], a, 0, 0, 0); \
      a = __builtin_amdgcn_mfma_f32_16x16x32_bf16(ahl[0], bhh[g][0], a, 0, 0, 0); \
      a = __builtin_amdgcn_mfma_f32_16x16x32_bf16(ahl[1], bhh[g][1], a, 0, 0, 0); \
      if (!FIRST) {                                                            \
        a = __builtin_amdgcn_mfma_f32_16x16x32_bf16(axh[P][0], bih[g][0], a, 0, 0, 0); \
        a = __builtin_amdgcn_mfma_f32_16x16x32_bf16(axh[P][1], bih[g][1], a, 0, 0, 0); \
        a = __builtin_amdgcn_mfma_f32_16x16x32_bf16(axl[P][0], bih[g][0], a, 0, 0, 0); \
        a = __builtin_amdgcn_mfma_f32_16x16x32_bf16(axl[P][1], bih[g][1], a, 0, 0, 0); \
      }                                                                        \
      accs[g] = a;                                                             \
    }                                                                          \
    float xcur[12];                                                            \
    if (FIRST) {                                                               \
      _Pragma("unroll")                                                        \
      for (int q = 0; q < 12; ++q) xcur[q] = xr[P][q];                         \
    }                                                                          \
    /* prefetch t+2 into parity slot P (consumed 2 steps later) */             \
    {                                                                          \
      int tp = (T0) + 2; if (tp >= T_LEN) tp = T_LEN - 1;                      \
      if (FIRST) {                                                             \
        _Pragma("unroll")                                                      \
        for (int r = 0; r < 4; ++r)                                            \
          _Pragma("unroll")                                                    \
          for (int i = 0; i < 3; ++i)                                          \
            xr[P][r * 3 + i] =                                                 \
                x_in[((size_t)(bbase + 4 * cg + r) * T_LEN + tp) * 3 + i];     \
      } else {                                                                 \
        const __bf16* ph = seq_hi + xrow + (size_t)tp * HDIM + xcol;           \
        const __bf16* pl = seq_lo + xrow + (size_t)tp * HDIM + xcol;           \
        axh[P][0] = *(const bf16x8*)(ph);                                      \
        axh[P][1] = *(const bf16x8*)(ph + 32);                                 \
        axl[P][0] = *(const bf16x8*)(pl);                                      \
        axl[P][1] = *(const bf16x8*)(pl + 32);                                 \
      }                                                                        \
    }                                                                          \
    /* epilogue: gates, cell update, h split+store */                          \
    _Pragma("unroll")                                                          \
    for (int r = 0; r < 4; ++r) {                                              \
      float gi = accs[0][r] + bias[0];                                         \
      float gf = accs[1][r] + bias[1];                                         \
      float gg = accs[2][r] + bias[2];                                         \
      float go = accs[3][r] + bias[3];                                         \
      if (FIRST) {                                                             \
        gi += xw[0] * xcur[r*3+0] + xw[1]  * xcur[r*3+1] + xw[2]  * xcur[r*3+2]; \
        gf += xw[3] * xcur[r*3+0] + xw[4]  * xcur[r*3+1] + xw[5]  * xcur[r*3+2]; \
        gg += xw[6] * xcur[r*3+0] + xw[7]  * xcur[r*3+1] + xw[8]  * xcur[r*3+2]; \
        go += xw[9] * xcur[r*3+0] + xw[10] * xcur[r*3+1] + xw[11] * xcur[r*3+2]; \
      }                                                                        \
      float iv = sigm(gi), fv = sigm(gf), gv = tanh_(gg), ov = sigm(go);       \
      cell[r] = fv * cell[r] + iv * gv;                                        \
      float hv = ov * tanh_(cell[r]);                                          \
      __bf16 h1 = (__bf16)hv;                                                  \
      __bf16 h2 = (__bf16)(hv - (float)h1);                                    \
      unsigned int hb = (unsigned int)__builtin_bit_cast(unsigned short, h1)   \
                      | ((unsigned int)__builtin_bit_cast(unsigned short, h2) << 16); \
      int mrow = 4 * cg + r;                                                   \
      hbuf[1 - (P)][mrow * 64 + (uu ^ ((mrow & 7) << 2))] = hb;                \
      size_t oidx = ((size_t)(bbase + mrow) * T_LEN + (T0)) * HDIM + uu;       \
      seq_hi[oidx] = h1;                                                       \
      seq_lo[oidx] = h2;                                                       \
    }                                                                          \
    __syncthreads();                                                           \
  }

template<bool FIRST>
__global__ __launch_bounds__(256, 1)
void lstm_mfma(const float* __restrict__ x_in,   // FIRST only: [B,T,3] f32
               const float* __restrict__ w_ih,   // FIRST: [256,3] else [256,64]
               const float* __restrict__ w_hh,   // [256,64]
               const float* __restrict__ b_ih,   // [256]
               const float* __restrict__ b_hh,   // [256]
               __bf16* __restrict__ seq_hi,      // [B,T,64] (in-place x for mid layers)
               __bf16* __restrict__ seq_lo)
{
    const int tid  = threadIdx.x;
    const int lane = tid & 63;
    const int wv   = tid >> 6;      // unit block: units [16wv, 16wv+16)
    const int nn   = lane & 15;     // A-row m / B-col n / D-col
    const int cg   = lane >> 4;     // k-group (A/B), D row group
    const int bbase = blockIdx.x * 16;
    const int uu = 16 * wv + nn;    // this lane's unit (D col)

    __shared__ __align__(16) unsigned int hbuf[2][16 * 64];  // packed hi|lo<<16, swizzled

    // ---- B-fragments of W_hh (and W_ih for mid layers), f32 -> bf16 ----
    bf16x8 bhh[4][2];
    const int grow = 16 * wv + nn;
#pragma unroll
    for (int g = 0; g < 4; ++g)
#pragma unroll
      for (int kk = 0; kk < 2; ++kk) {
        const float* wp = w_hh + (size_t)(64 * g + grow) * 64 + kk * 32 + 8 * cg;
#pragma unroll
        for (int e = 0; e < 8; ++e) bhh[g][kk][e] = (__bf16)wp[e];
      }
    bf16x8 bih[4][2];
    float xw[12];
    if (FIRST) {
#pragma unroll
      for (int g = 0; g < 4; ++g)
#pragma unroll
        for (int i = 0; i < 3; ++i) xw[g * 3 + i] = w_ih[(64 * g + grow) * 3 + i];
    } else {
#pragma unroll
      for (int g = 0; g < 4; ++g)
#pragma unroll
        for (int kk = 0; kk < 2; ++kk) {
          const float* wp = w_ih + (size_t)(64 * g + grow) * 64 + kk * 32 + 8 * cg;
#pragma unroll
          for (int e = 0; e < 8; ++e) bih[g][kk][e] = (__bf16)wp[e];
        }
    }
    float bias[4];
#pragma unroll
    for (int g = 0; g < 4; ++g) {
      int row = 64 * g + grow;
      bias[g] = b_ih[row] + b_hh[row];
    }

    // zero h(-1) buffer
#pragma unroll
    for (int q = 0; q < 4; ++q) hbuf[0][tid * 4 + q] = 0u;

    float cell[4] = {0.f, 0.f, 0.f, 0.f};

    // ---- prefetch x for t=0,1 (parity slots 0,1) ----
    const size_t xrow = (size_t)(bbase + nn) * T_LEN * HDIM;  // A-row m = nn
    const int xcol = 8 * cg;
    bf16x8 axh[2][2], axl[2][2];
    float xr[2][12];
    if (FIRST) {
#pragma unroll
      for (int p = 0; p < 2; ++p)
#pragma unroll
        for (int r = 0; r < 4; ++r)
#pragma unroll
          for (int i = 0; i < 3; ++i)
            xr[p][r * 3 + i] = x_in[((size_t)(bbase + 4 * cg + r) * T_LEN + p) * 3 + i];
    } else {
#pragma unroll
      for (int p = 0; p < 2; ++p) {
        const __bf16* ph = seq_hi + xrow + (size_t)p * HDIM + xcol;
        const __bf16* pl = seq_lo + xrow + (size_t)p * HDIM + xcol;
        axh[p][0] = *(const bf16x8*)(ph);
        axh[p][1] = *(const bf16x8*)(ph + 32);
        axl[p][0] = *(const bf16x8*)(pl);
        axl[p][1] = *(const bf16x8*)(pl + 32);
      }
    }
    __syncthreads();

    for (int t = 0; t < T_LEN; t += 2) {
      STEP(t, 0);
      STEP(t + 1, 1);
    }
}

// FC head: out[b] = fc2_b + fc2_w . relu(fc1_b + fc1_w . h_T[b])
__global__ __launch_bounds__(256, 1)
void fc_head(const __bf16* __restrict__ seq_hi, const __bf16* __restrict__ seq_lo,
             const float* __restrict__ fc1_w, const float* __restrict__ fc1_b,
             const float* __restrict__ fc2_w, const float* __restrict__ fc2_b,
             float* __restrict__ out)
{
    __shared__ float w1[FC1 * HDIM];
    __shared__ float b1[FC1];
    __shared__ float w2[FC1];
    const int tid = threadIdx.x;
    for (int i = tid; i < FC1 * HDIM; i += 256) w1[i] = fc1_w[i];
    if (tid < FC1) { b1[tid] = fc1_b[tid]; w2[tid] = fc2_w[tid]; }
    __syncthreads();

    const int b = blockIdx.x * 256 + tid;
    const size_t base = ((size_t)b * T_LEN + (T_LEN - 1)) * HDIM;
    float h[HDIM];
#pragma unroll
    for (int q = 0; q < HDIM; ++q) h[q] = (float)seq_hi[base + q] + (float)seq_lo[base + q];
    float acc2 = fc2_b[0];
    for (int m = 0; m < FC1; ++m) {
      float a = b1[m];
#pragma unroll
      for (int q = 0; q < HDIM; ++q) a += w1[m * HDIM + q] * h[q];
      acc2 += w2[m] * fmaxf(a, 0.0f);
    }
    out[b] = acc2;
}

extern "C" void kernel_launch(void* const* d_in, const int* in_sizes, int n_in,
                              void* d_out, int out_size, void* d_ws, size_t ws_size,
                              hipStream_t stream) {
    const float* x         = (const float*)d_in[0];
    const float* w_ih0     = (const float*)d_in[1];
    const float* w_ih_rest = (const float*)d_in[2];
    const float* w_hh      = (const float*)d_in[3];
    const float* b_ih      = (const float*)d_in[4];
    const float* b_hh      = (const float*)d_in[5];
    const float* fc1_w     = (const float*)d_in[6];
    const float* fc1_b     = (const float*)d_in[7];
    const float* fc2_w     = (const float*)d_in[8];
    const float* fc2_b     = (const float*)d_in[9];
    float* out = (float*)d_out;

    __bf16* seq_hi = (__bf16*)d_ws;                                  // 128 MiB
    __bf16* seq_lo = seq_hi + (size_t)B_TOT * T_LEN * HDIM;          // 128 MiB

    lstm_mfma<true><<<dim3(B_TOT / 16), dim3(256), 0, stream>>>(
        x, w_ih0, w_hh, b_ih, b_hh, seq_hi, seq_lo);
    for (int l = 1; l < 5; ++l) {
      lstm_mfma<false><<<dim3(B_TOT / 16), dim3(256), 0, stream>>>(
          nullptr,
          w_ih_rest + (size_t)(l - 1) * 256 * HDIM,
          w_hh + (size_t)l * 256 * HDIM,
          b_ih + (size_t)l * 256,
          b_hh + (size_t)l * 256,
          seq_hi, seq_lo);
    }
    fc_head<<<dim3(B_TOT / 256), dim3(256), 0, stream>>>(
        seq_hi, seq_lo, fc1_w, fc1_b, fc2_w, fc2_b, out);
}